// Round 5
// baseline (481.662 us; speedup 1.0000x reference)
//
#include <hip/hip_runtime.h>
#include <hip/hip_bf16.h>

// SeRNN forward: 6 channel-wise LSTMs (H=32) over T=256, B=1024, then MLP head.
// Outputs (concat): out [B,2] (2048 floats) then x7 [B,T,192].
//
// R2: VALU-bound (VALUBusy 69%, MfmaUtil 0, HBM 8%): 330 us.
// R4: tanh-via-sigmoid merge, 6 trans/step, no cndmask: 287 us, VALUBusy 65%.
// R5: matvec is the wall (64 scalar v_fma issue slots/step). Pack gate pair
//     (g0,g1) into (lo,hi) of v_pk_fma_f32 with op_sel broadcasting the shared
//     h scalar -> 32 packed FMA/step. Tests whether gfx950 packed fp32 is
//     full-rate (CDNA2 was; CDNA3/4 unknown). Neutral if half-rate.

#define Bv 1024
#define Tv 256
#define Cv 6
#define Hv 32
#define Gv 128   // 4*H, PyTorch gate order i,f,g,o

#define L2E 1.442695041f   // log2(e)

typedef __attribute__((ext_vector_type(2))) float f32x2;
typedef __attribute__((ext_vector_type(4))) float f32x4;

// acc.lo += w.lo*h.lo + ..., acc.hi += w.hi*h.lo  (h LO broadcast to both halves)
#define PK_EVEN(acc, w, h) \
    asm("v_pk_fma_f32 %0, %1, %2, %0 op_sel:[0,0,0] op_sel_hi:[1,0,1]" \
        : "+v"(acc) : "v"(w), "v"(h))
// acc.lo += w.lo*h.hi, acc.hi += w.hi*h.hi  (h HI broadcast to both halves)
#define PK_ODD(acc, w, h) \
    asm("v_pk_fma_f32 %0, %1, %2, %0 op_sel:[0,1,0] op_sel_hi:[1,1,1]" \
        : "+v"(acc) : "v"(w), "v"(h))

// One wave per (b,c) sequence. Lane l owns gate rows l (->g0=lo) and l+64
// (->g1=hi) as packed f32x2 weights. h state broadcast via per-wave LDS.
__global__ __launch_bounds__(256) void lstm_kernel(
    const float* __restrict__ x,      // [B,T,C]
    const float* __restrict__ w_ih,   // [C,G]
    const float* __restrict__ w_hh,   // [C,G,H]
    const float* __restrict__ b_ih,   // [C,G]
    const float* __restrict__ b_hh,   // [C,G]
    float* __restrict__ x7)           // [B,T,C*H]
{
    __shared__ float hbuf[4][Hv];

    const int wave = threadIdx.x >> 6;
    const int lane = threadIdx.x & 63;
    const int c    = blockIdx.x % Cv;            // block-uniform channel
    const int b    = (blockIdx.x / Cv) * 4 + wave;

    // ---- weights packed: wp[j] = (w_hh[row=lane][j], w_hh[row=lane+64][j]) ----
    f32x2 wp[Hv];
    const float* whc = w_hh + (size_t)c * (Gv * Hv);
    #pragma unroll
    for (int j4 = 0; j4 < Hv / 4; ++j4) {
        float4 a = *(const float4*)(whc + lane * Hv + j4 * 4);
        float4 q = *(const float4*)(whc + (lane + 64) * Hv + j4 * 4);
        wp[j4*4+0] = (f32x2){a.x, q.x};
        wp[j4*4+1] = (f32x2){a.y, q.y};
        wp[j4*4+2] = (f32x2){a.z, q.z};
        wp[j4*4+3] = (f32x2){a.w, q.w};
    }
    const float wi0 = w_ih[c * Gv + lane];
    const float wi1 = w_ih[c * Gv + lane + 64];
    const float bb0 = b_ih[c * Gv + lane] + b_hh[c * Gv + lane];
    const float bb1 = b_ih[c * Gv + lane + 64] + b_hh[c * Gv + lane + 64];

    // Per-lane activation constants:
    //  lanes <32: g1 is the g-gate -> tanh(g) = 2*sig(2g)-1
    //  lanes>=32: g1 is the o-gate -> sig(o)
    const bool  lo   = (lane < 32);
    const float nsc1 = lo ? (-2.0f * L2E) : (-L2E);
    const float fa   = lo ? 2.0f : 1.0f;
    const float fb   = lo ? -1.0f : 0.0f;

    if (lane < Hv) hbuf[wave][lane] = 0.0f;   // h0 = 0 (same-wave DS ordering)
    float cc = 0.0f;                          // real cell state only in lanes<32

    const float* xp = x + (size_t)b * Tv * Cv + c;
    float* op = x7 + (size_t)b * Tv * (Cv * Hv) + c * Hv + (lane & 31);

    float xt = xp[0];
    for (int t = 0; t < Tv; ++t) {
        // software-pipeline next x_t (uniform-address scalar load)
        float xn = (t + 1 < Tv) ? xp[(size_t)(t + 1) * Cv] : 0.0f;

        // 4 packed accumulator chains, 8 deep each
        f32x2 ac0 = {fmaf(xt, wi0, bb0), fmaf(xt, wi1, bb1)};
        f32x2 ac1 = {0.f, 0.f}, ac2 = {0.f, 0.f}, ac3 = {0.f, 0.f};
        const f32x4* hb4 = (const f32x4*)hbuf[wave];
        #pragma unroll
        for (int q = 0; q < Hv / 4; ++q) {
            f32x4 h4 = hb4[q];                 // broadcast ds_read_b128
            f32x2 hA = {h4.x, h4.y};
            f32x2 hB = {h4.z, h4.w};
            PK_EVEN(ac0, wp[q*4+0], hA);       // uses h4.x
            PK_ODD (ac1, wp[q*4+1], hA);       // uses h4.y
            PK_EVEN(ac2, wp[q*4+2], hB);       // uses h4.z
            PK_ODD (ac3, wp[q*4+3], hB);       // uses h4.w
        }
        f32x2 gs = (ac0 + ac1) + (ac2 + ac3);
        float g0 = gs.x;        // lanes<32: i-gate,  lanes>=32: f-gate
        float g1 = gs.y;        // lanes<32: g-gate,  lanes>=32: o-gate

        // s0 = sigmoid(g0): sig(i) | sig(f)
        float e0 = __builtin_amdgcn_exp2f(g0 * -L2E);
        float s0 = __builtin_amdgcn_rcpf(1.0f + e0);
        // to = tanh(g) | sig(o)  via one shared exp+rcp
        float e1 = __builtin_amdgcn_exp2f(g1 * nsc1);
        float u1 = __builtin_amdgcn_rcpf(1.0f + e1);
        float to = fmaf(u1, fa, fb);

        // lanes<32 gather sig(f), sig(o) from the high half (hi half keeps
        // bounded garbage, never read).
        float f_s = __shfl_xor(s0, 32);
        float o_s = __shfl_xor(to, 32);

        cc = fmaf(f_s, cc, s0 * to);          // lo: sig(f)*c + sig(i)*tanh(g)
        // tanh(cc) = 2*sig(2cc)-1
        float e2 = __builtin_amdgcn_exp2f(cc * (-2.0f * L2E));
        float u2 = __builtin_amdgcn_rcpf(1.0f + e2);
        float th = fmaf(u2, 2.0f, -1.0f);
        float hn = o_s * th;                  // lo: sig(o)*tanh(cc)

        if (lane < Hv) {
            hbuf[wave][lane] = hn;            // next step's broadcast source
            op[(size_t)t * (Cv * Hv)] = hn;   // x7[b,t,c*32+lane]
        }
        xt = xn;
    }
}

// MLP head on x7[:, T-1, :]: fc1(192->64)+relu, fc3(64->64)+relu, fc2(64->2)
__global__ __launch_bounds__(64) void head_kernel(
    const float* __restrict__ x7,
    const float* __restrict__ w1, const float* __restrict__ b1,
    const float* __restrict__ w3, const float* __restrict__ b3,
    const float* __restrict__ w2, const float* __restrict__ b2,
    float* __restrict__ out)
{
    const int b   = blockIdx.x;
    const int tid = threadIdx.x;
    __shared__ float xr[Cv * Hv];
    __shared__ float h1[64];
    __shared__ float h2[64];

    const float* xrow = x7 + ((size_t)b * Tv + (Tv - 1)) * (Cv * Hv);
    if (tid < 48) ((float4*)xr)[tid] = ((const float4*)xrow)[tid];
    __syncthreads();

    // fc1: 192-dot as 48 float4 terms over 4 independent accumulators
    float acc[4] = {0.f, 0.f, 0.f, 0.f};
    const float4* w4 = (const float4*)(w1 + tid * (Cv * Hv));
    const float4* x4 = (const float4*)xr;
    #pragma unroll
    for (int k = 0; k < 48; ++k) {
        float4 w = w4[k], xv = x4[k];
        acc[k & 3] += (w.x * xv.x + w.y * xv.y) + (w.z * xv.z + w.w * xv.w);
    }
    h1[tid] = fmaxf((acc[0] + acc[1]) + (acc[2] + acc[3]) + b1[tid], 0.0f);
    __syncthreads();

    // fc3: 64-dot as 16 float4 terms
    float bcc[4] = {0.f, 0.f, 0.f, 0.f};
    const float4* w34 = (const float4*)(w3 + tid * 64);
    const float4* h14 = (const float4*)h1;
    #pragma unroll
    for (int k = 0; k < 16; ++k) {
        float4 w = w34[k], hv = h14[k];
        bcc[k & 3] += (w.x * hv.x + w.y * hv.y) + (w.z * hv.z + w.w * hv.w);
    }
    h2[tid] = fmaxf((bcc[0] + bcc[1]) + (bcc[2] + bcc[3]) + b3[tid], 0.0f);
    __syncthreads();

    if (tid < 2) {
        float a2 = b2[tid];
        const float* w2r = w2 + tid * 64;
        #pragma unroll 4
        for (int k = 0; k < 64; ++k) a2 += w2r[k] * h2[k];
        out[b * 2 + tid] = a2;
    }
}

extern "C" void kernel_launch(void* const* d_in, const int* in_sizes, int n_in,
                              void* d_out, int out_size, void* d_ws, size_t ws_size,
                              hipStream_t stream) {
    const float* x    = (const float*)d_in[0];
    const float* w_ih = (const float*)d_in[1];
    const float* w_hh = (const float*)d_in[2];
    const float* b_ih = (const float*)d_in[3];
    const float* b_hh = (const float*)d_in[4];
    const float* w1   = (const float*)d_in[5];
    const float* b1   = (const float*)d_in[6];
    const float* w3   = (const float*)d_in[7];
    const float* b3   = (const float*)d_in[8];
    const float* w2   = (const float*)d_in[9];
    const float* b2   = (const float*)d_in[10];

    float* out = (float*)d_out;
    float* x7  = out + (size_t)Bv * 2;   // tuple order: (out [B,2], x7 [B,T,192])

    lstm_kernel<<<dim3((Bv / 4) * Cv), dim3(256), 0, stream>>>(x, w_ih, w_hh, b_ih, b_hh, x7);
    head_kernel<<<dim3(Bv), dim3(64), 0, stream>>>(x7, w1, b1, w3, b3, w2, b2, out);
}

// Round 7
// 419.313 us; speedup vs baseline: 1.1487x; 1.1487x over previous
//
#include <hip/hip_runtime.h>
#include <hip/hip_bf16.h>

// SeRNN forward: 6 channel-wise LSTMs (H=32) over T=256, B=1024, then MLP head.
// Outputs (concat): out [B,2] (2048 floats) then x7 [B,T,192].
//
// R2: VALU-bound (VALUBusy 69%, MfmaUtil 0, HBM 8%): 330 us.
// R4: tanh-via-sigmoid merge, 6 trans/step: 287 us, VALUBusy 65%, occ 42%.
// R5: v_pk_fma_f32 REGRESSED (324 us) -> packed fp32 half-rate. Reverted.
// R6: fdot2 attempt died on a cvt_pkrtz return-type mismatch (compile error).
// R7: same fdot2 design, bitcast fix: v_dot2_f32_f16 full-rate VOP3P ->
//     32 dot2/step instead of 64 FMA, weights 64->32 VGPRs, h-reads 8->4.
//     Precision gamble: f16-rounded w/h in recurrence, predicted absmax ~3-5e-3.

#define Bv 1024
#define Tv 256
#define Cv 6
#define Hv 32
#define Gv 128   // 4*H, PyTorch gate order i,f,g,o

#define L2E 1.442695041f   // log2(e)

#if __has_builtin(__builtin_amdgcn_fdot2)
#define USE_DOT2 1
#else
#define USE_DOT2 0
#endif

typedef _Float16 h2 __attribute__((ext_vector_type(2)));
typedef _Float16 h8 __attribute__((ext_vector_type(8)));

// One wave per (b,c) sequence. Lane l owns gate rows l (g0) and l+64 (g1).
// h state broadcast via per-wave LDS buffer (same-address reads, f16 pairs).
__global__ __launch_bounds__(256) void lstm_kernel(
    const float* __restrict__ x,      // [B,T,C]
    const float* __restrict__ w_ih,   // [C,G]
    const float* __restrict__ w_hh,   // [C,G,H]
    const float* __restrict__ b_ih,   // [C,G]
    const float* __restrict__ b_hh,   // [C,G]
    float* __restrict__ x7)           // [B,T,C*H]
{
    const int wave = threadIdx.x >> 6;
    const int lane = threadIdx.x & 63;
    const int c    = blockIdx.x % Cv;            // block-uniform channel
    const int b    = (blockIdx.x / Cv) * 4 + wave;

    const float* whc = w_hh + (size_t)c * (Gv * Hv);

#if USE_DOT2
    __shared__ h2 hb16[4][Hv / 2];               // h as f16 pairs, 64 B/wave
    // weights as f16 pairs (RNE at init): wpa = row lane, wpb = row lane+64
    h2 wpa[Hv / 2], wpb[Hv / 2];
    #pragma unroll
    for (int j4 = 0; j4 < Hv / 4; ++j4) {
        float4 a = *(const float4*)(whc + lane * Hv + j4 * 4);
        float4 q = *(const float4*)(whc + (lane + 64) * Hv + j4 * 4);
        wpa[j4*2+0] = h2{(_Float16)a.x, (_Float16)a.y};
        wpa[j4*2+1] = h2{(_Float16)a.z, (_Float16)a.w};
        wpb[j4*2+0] = h2{(_Float16)q.x, (_Float16)q.y};
        wpb[j4*2+1] = h2{(_Float16)q.z, (_Float16)q.w};
    }
    if (lane < Hv / 2) hb16[wave][lane] = (h2)(_Float16)0;  // h0 = 0
#else
    __shared__ float hbuf[4][Hv];
    float w0[Hv], w1r[Hv];
    #pragma unroll
    for (int j4 = 0; j4 < Hv / 4; ++j4) {
        float4 a = *(const float4*)(whc + lane * Hv + j4 * 4);
        float4 q = *(const float4*)(whc + (lane + 64) * Hv + j4 * 4);
        w0[j4*4+0] = a.x; w0[j4*4+1] = a.y; w0[j4*4+2] = a.z; w0[j4*4+3] = a.w;
        w1r[j4*4+0] = q.x; w1r[j4*4+1] = q.y; w1r[j4*4+2] = q.z; w1r[j4*4+3] = q.w;
    }
    if (lane < Hv) hbuf[wave][lane] = 0.0f;
#endif

    const float wi0 = w_ih[c * Gv + lane];
    const float wi1 = w_ih[c * Gv + lane + 64];
    const float bb0 = b_ih[c * Gv + lane] + b_hh[c * Gv + lane];
    const float bb1 = b_ih[c * Gv + lane + 64] + b_hh[c * Gv + lane + 64];

    // Per-lane activation constants:
    //  lanes <32: g1 is the g-gate -> tanh(g) = 2*sig(2g)-1
    //  lanes>=32: g1 is the o-gate -> sig(o)
    const bool  lo   = (lane < 32);
    const float nsc1 = lo ? (-2.0f * L2E) : (-L2E);
    const float fa   = lo ? 2.0f : 1.0f;
    const float fb   = lo ? -1.0f : 0.0f;

    float cc = 0.0f;                          // real cell state only in lanes<32

    const float* xp = x + (size_t)b * Tv * Cv + c;
    float* op = x7 + (size_t)b * Tv * (Cv * Hv) + c * Hv + (lane & 31);

    float xt = xp[0];
    for (int t = 0; t < Tv; ++t) {
        // software-pipeline next x_t (uniform-address scalar load)
        float xn = (t + 1 < Tv) ? xp[(size_t)(t + 1) * Cv] : 0.0f;

        float g0, g1;
#if USE_DOT2
        // 4 accumulator chains, 8 dot2 deep each; f32 accumulate
        float a00 = fmaf(xt, wi0, bb0), a01 = 0.0f;
        float a10 = fmaf(xt, wi1, bb1), a11 = 0.0f;
        const h8* hp8 = (const h8*)hb16[wave];
        #pragma unroll
        for (int q4 = 0; q4 < 4; ++q4) {
            h8 hv = hp8[q4];                   // broadcast ds_read_b128 (8 h)
            h2 p0 = {hv[0], hv[1]}, p1 = {hv[2], hv[3]};
            h2 p2 = {hv[4], hv[5]}, p3 = {hv[6], hv[7]};
            a00 = __builtin_amdgcn_fdot2(wpa[q4*4+0], p0, a00, false);
            a01 = __builtin_amdgcn_fdot2(wpa[q4*4+1], p1, a01, false);
            a10 = __builtin_amdgcn_fdot2(wpb[q4*4+0], p0, a10, false);
            a11 = __builtin_amdgcn_fdot2(wpb[q4*4+1], p1, a11, false);
            a00 = __builtin_amdgcn_fdot2(wpa[q4*4+2], p2, a00, false);
            a01 = __builtin_amdgcn_fdot2(wpa[q4*4+3], p3, a01, false);
            a10 = __builtin_amdgcn_fdot2(wpb[q4*4+2], p2, a10, false);
            a11 = __builtin_amdgcn_fdot2(wpb[q4*4+3], p3, a11, false);
        }
        g0 = a00 + a01;         // lanes<32: i-gate,  lanes>=32: f-gate
        g1 = a10 + a11;         // lanes<32: g-gate,  lanes>=32: o-gate
#else
        float g0a = fmaf(xt, wi0, bb0), g0b = 0.0f;
        float g1a = fmaf(xt, wi1, bb1), g1b = 0.0f;
        const float4* hb4 = (const float4*)hbuf[wave];
        #pragma unroll
        for (int q4 = 0; q4 < Hv / 4; ++q4) {
            float4 h4 = hb4[q4];
            g0a += w0[q4*4+0] * h4.x;  g1a += w1r[q4*4+0] * h4.x;
            g0b += w0[q4*4+1] * h4.y;  g1b += w1r[q4*4+1] * h4.y;
            g0a += w0[q4*4+2] * h4.z;  g1a += w1r[q4*4+2] * h4.z;
            g0b += w0[q4*4+3] * h4.w;  g1b += w1r[q4*4+3] * h4.w;
        }
        g0 = g0a + g0b;
        g1 = g1a + g1b;
#endif

        // s0 = sigmoid(g0): sig(i) | sig(f)
        float e0 = __builtin_amdgcn_exp2f(g0 * -L2E);
        float s0 = __builtin_amdgcn_rcpf(1.0f + e0);
        // to = tanh(g) | sig(o)  via one shared exp+rcp
        float e1 = __builtin_amdgcn_exp2f(g1 * nsc1);
        float u1 = __builtin_amdgcn_rcpf(1.0f + e1);
        float to = fmaf(u1, fa, fb);

        // lanes<32 gather sig(f), sig(o) from the high half (hi half keeps
        // bounded garbage, never read).
        float f_s = __shfl_xor(s0, 32);
        float o_s = __shfl_xor(to, 32);

        cc = fmaf(f_s, cc, s0 * to);          // lo: sig(f)*c + sig(i)*tanh(g)
        // tanh(cc) = 2*sig(2cc)-1
        float e2 = __builtin_amdgcn_exp2f(cc * (-2.0f * L2E));
        float u2 = __builtin_amdgcn_rcpf(1.0f + e2);
        float th = fmaf(u2, 2.0f, -1.0f);
        float hn = o_s * th;                  // lo: sig(o)*tanh(cc)

#if USE_DOT2
        float hnb = __shfl_xor(hn, 1);        // neighbor's h for pair packing
        if (lane < Hv) {
            op[(size_t)t * (Cv * Hv)] = hn;   // x7 gets full-precision f32 h
            if (!(lane & 1)) {                // even lanes pack (h[2k],h[2k+1])
                auto pk = __builtin_amdgcn_cvt_pkrtz(hn, hnb);  // __fp16 x2
                hb16[wave][lane >> 1] = __builtin_bit_cast(h2, pk);
            }
        }
#else
        if (lane < Hv) {
            hbuf[wave][lane] = hn;
            op[(size_t)t * (Cv * Hv)] = hn;
        }
#endif
        xt = xn;
    }
}

// MLP head on x7[:, T-1, :]: fc1(192->64)+relu, fc3(64->64)+relu, fc2(64->2)
__global__ __launch_bounds__(64) void head_kernel(
    const float* __restrict__ x7,
    const float* __restrict__ w1, const float* __restrict__ b1,
    const float* __restrict__ w3, const float* __restrict__ b3,
    const float* __restrict__ w2, const float* __restrict__ b2,
    float* __restrict__ out)
{
    const int b   = blockIdx.x;
    const int tid = threadIdx.x;
    __shared__ float xr[Cv * Hv];
    __shared__ float h1[64];
    __shared__ float h2s[64];

    const float* xrow = x7 + ((size_t)b * Tv + (Tv - 1)) * (Cv * Hv);
    if (tid < 48) ((float4*)xr)[tid] = ((const float4*)xrow)[tid];
    __syncthreads();

    // fc1: 192-dot as 48 float4 terms over 4 independent accumulators
    float acc[4] = {0.f, 0.f, 0.f, 0.f};
    const float4* w4 = (const float4*)(w1 + tid * (Cv * Hv));
    const float4* x4 = (const float4*)xr;
    #pragma unroll
    for (int k = 0; k < 48; ++k) {
        float4 w = w4[k], xv = x4[k];
        acc[k & 3] += (w.x * xv.x + w.y * xv.y) + (w.z * xv.z + w.w * xv.w);
    }
    h1[tid] = fmaxf((acc[0] + acc[1]) + (acc[2] + acc[3]) + b1[tid], 0.0f);
    __syncthreads();

    // fc3: 64-dot as 16 float4 terms
    float bcc[4] = {0.f, 0.f, 0.f, 0.f};
    const float4* w34 = (const float4*)(w3 + tid * 64);
    const float4* h14 = (const float4*)h1;
    #pragma unroll
    for (int k = 0; k < 16; ++k) {
        float4 w = w34[k], hv = h14[k];
        bcc[k & 3] += (w.x * hv.x + w.y * hv.y) + (w.z * hv.z + w.w * hv.w);
    }
    h2s[tid] = fmaxf((bcc[0] + bcc[1]) + (bcc[2] + bcc[3]) + b3[tid], 0.0f);
    __syncthreads();

    if (tid < 2) {
        float a2 = b2[tid];
        const float* w2r = w2 + tid * 64;
        #pragma unroll 4
        for (int k = 0; k < 64; ++k) a2 += w2r[k] * h2s[k];
        out[b * 2 + tid] = a2;
    }
}

extern "C" void kernel_launch(void* const* d_in, const int* in_sizes, int n_in,
                              void* d_out, int out_size, void* d_ws, size_t ws_size,
                              hipStream_t stream) {
    const float* x    = (const float*)d_in[0];
    const float* w_ih = (const float*)d_in[1];
    const float* w_hh = (const float*)d_in[2];
    const float* b_ih = (const float*)d_in[3];
    const float* b_hh = (const float*)d_in[4];
    const float* w1   = (const float*)d_in[5];
    const float* b1   = (const float*)d_in[6];
    const float* w3   = (const float*)d_in[7];
    const float* b3   = (const float*)d_in[8];
    const float* w2   = (const float*)d_in[9];
    const float* b2   = (const float*)d_in[10];

    float* out = (float*)d_out;
    float* x7  = out + (size_t)Bv * 2;   // tuple order: (out [B,2], x7 [B,T,192])

    lstm_kernel<<<dim3((Bv / 4) * Cv), dim3(256), 0, stream>>>(x, w_ih, w_hh, b_ih, b_hh, x7);
    head_kernel<<<dim3(Bv), dim3(64), 0, stream>>>(x7, w1, b1, w3, b3, w2, b2, out);
}

// Round 8
// 395.361 us; speedup vs baseline: 1.2183x; 1.0606x over previous
//
#include <hip/hip_runtime.h>
#include <hip/hip_bf16.h>

// SeRNN forward: 6 channel-wise LSTMs (H=32) over T=256, B=1024, then MLP head.
// Outputs (concat): out [B,2] (2048 floats) then x7 [B,T,192].
//
// R2: VALU-bound baseline 330 us. R4: trans-op merge 287 us. R5: pk_fma
// regressed (reverted). R7: fdot2 matvec 255 us, VALUBusy 72%, absmax 2^-9
// (f16 inputs + f32 accum proven safe).
// R8: MFMA restructure. Group = 16 sequences (one channel), 2 waves/group:
//     wave w owns units w*16..w*16+15 = 4 gate-tiles (i,f,g,o). Per step:
//     gates = mfma_f32_16x16x32_f16(A=W_hh rows, B=h[32x16]) x4, C-in =
//     bias + x_t*w_ih. Activations are lane-local (i,f,g,o of a unit share
//     lane+reg across the 4 acc tiles). h round-trips through a 2-buffer
//     LDS tile ([n][k] padded to 40 f16/row), one __syncthreads per step.
//     A/B k-slot mapping chosen as k=(lane>>4)*8+j for BOTH operands
//     (k-permutation invariance makes any consistent bijection correct).

#define Bv 1024
#define Tv 256
#define Cv 6
#define Hv 32
#define Gv 128   // 4*H, PyTorch gate order i,f,g,o

#define L2E 1.442695041f   // log2(e)

typedef _Float16 f16x8 __attribute__((ext_vector_type(8)));
typedef float f32x4v __attribute__((ext_vector_type(4)));

__device__ __forceinline__ float fsig(float v) {
    return __builtin_amdgcn_rcpf(1.0f + __builtin_amdgcn_exp2f(v * -L2E));
}
__device__ __forceinline__ float ftanh2(float v) {  // tanh(x) = 2*sig(2x)-1
    float u = __builtin_amdgcn_rcpf(1.0f + __builtin_amdgcn_exp2f(v * (-2.0f * L2E)));
    return fmaf(u, 2.0f, -1.0f);
}

__global__ __launch_bounds__(128) void lstm_kernel(
    const float* __restrict__ x,      // [B,T,C]
    const float* __restrict__ w_ih,   // [C,G]
    const float* __restrict__ w_hh,   // [C,G,H]
    const float* __restrict__ b_ih,   // [C,G]
    const float* __restrict__ b_hh,   // [C,G]
    float* __restrict__ x7)           // [B,T,C*H]
{
    // h state: [buf][batch n][unit k], row padded 32->40 f16 (80 B) to break
    // the n<->n+8 bank alias down to free 2-way.
    __shared__ _Float16 hlds[2][16][40];

    const int tid  = threadIdx.x;
    const int wv   = tid >> 6;        // 0/1: unit half (units wv*16..wv*16+15)
    const int lane = tid & 63;
    const int r16  = lane & 15;       // A-row within tile / B-col (batch)
    const int grp  = lane >> 4;       // k-group and D-row group

    const int c  = blockIdx.x % Cv;               // channel
    const int nb = (blockIdx.x / Cv) * 16;        // batch base of this group

    // zero both h buffers (h0 = 0)
    {
        _Float16* hz = &hlds[0][0][0];
        for (int i = tid; i < 2 * 16 * 40; i += 128) hz[i] = (_Float16)0.0f;
    }

    // ---- A fragments: afrag[q] = W_hh[c][q*32+wv*16+r16][grp*8 + j] as f16 ----
    const float* whc = w_hh + (size_t)c * (Gv * Hv);
    f16x8 afrag[4];
    #pragma unroll
    for (int q = 0; q < 4; ++q) {
        const float* wr = whc + (q * 32 + wv * 16 + r16) * Hv + grp * 8;
        float4 wa = *(const float4*)(wr);
        float4 wb = *(const float4*)(wr + 4);
        f16x8 a;
        a[0] = (_Float16)wa.x; a[1] = (_Float16)wa.y;
        a[2] = (_Float16)wa.z; a[3] = (_Float16)wa.w;
        a[4] = (_Float16)wb.x; a[5] = (_Float16)wb.y;
        a[6] = (_Float16)wb.z; a[7] = (_Float16)wb.w;
        afrag[q] = a;
    }
    // ---- bias + w_ih at D positions: rows q*32 + wv*16 + grp*4 + r ----
    float4 bias4[4], wih4[4];
    #pragma unroll
    for (int q = 0; q < 4; ++q) {
        const int rb = q * 32 + wv * 16 + grp * 4;
        float4 bi = *(const float4*)(b_ih + c * Gv + rb);
        float4 bh = *(const float4*)(b_hh + c * Gv + rb);
        bias4[q] = make_float4(bi.x + bh.x, bi.y + bh.y, bi.z + bh.z, bi.w + bh.w);
        wih4[q]  = *(const float4*)(w_ih + c * Gv + rb);
    }

    float cst[4] = {0.0f, 0.0f, 0.0f, 0.0f};      // cell state, units grp*4+r
    const float* xp = x + ((size_t)(nb + r16) * Tv) * Cv + c;
    float* op = x7 + ((size_t)(nb + r16) * Tv) * (Cv * Hv) + c * Hv + wv * 16 + grp * 4;

    __syncthreads();

    float xt = xp[0];
    int p = 0;
    for (int t = 0; t < Tv; ++t) {
        // prefetch next x_t (clamped at the end; value unused then)
        int tn = (t + 1 < Tv) ? (t + 1) : (Tv - 1);
        float xn = xp[tn * Cv];

        // B fragment: h[k = grp*8 + j][n = r16] from current buffer
        f16x8 bfrag = *(const f16x8*)(&hlds[p][r16][grp * 8]);

        f32x4v acc[4];
        #pragma unroll
        for (int q = 0; q < 4; ++q) {
            acc[q][0] = fmaf(xt, wih4[q].x, bias4[q].x);
            acc[q][1] = fmaf(xt, wih4[q].y, bias4[q].y);
            acc[q][2] = fmaf(xt, wih4[q].z, bias4[q].z);
            acc[q][3] = fmaf(xt, wih4[q].w, bias4[q].w);
            acc[q] = __builtin_amdgcn_mfma_f32_16x16x32_f16(afrag[q], bfrag, acc[q], 0, 0, 0);
        }

        // activations: lane-local; unit u = wv*16 + grp*4 + r, batch nb + r16
        float h4[4];
        #pragma unroll
        for (int r = 0; r < 4; ++r) {
            float i_s = fsig(acc[0][r]);
            float f_s = fsig(acc[1][r]);
            float g_t = ftanh2(acc[2][r]);
            float o_s = fsig(acc[3][r]);
            float cr  = fmaf(f_s, cst[r], i_s * g_t);
            cst[r] = cr;
            h4[r] = o_s * ftanh2(cr);
        }

        // x7[b][t][c*32 + u]: 4 contiguous units -> one dwordx4
        *(float4*)(op + (size_t)t * (Cv * Hv)) = make_float4(h4[0], h4[1], h4[2], h4[3]);

        // pack h to f16, write into the other buffer for step t+1
        auto pk0 = __builtin_amdgcn_cvt_pkrtz(h4[0], h4[1]);   // __fp16x2
        auto pk1 = __builtin_amdgcn_cvt_pkrtz(h4[2], h4[3]);
        uint2 pk = make_uint2(__builtin_bit_cast(unsigned int, pk0),
                              __builtin_bit_cast(unsigned int, pk1));
        *(uint2*)(&hlds[p ^ 1][r16][wv * 16 + grp * 4]) = pk;

        __syncthreads();   // h(t+1) visible to both waves; buffers swap
        p ^= 1;
        xt = xn;
    }
}

// MLP head on x7[:, T-1, :]: fc1(192->64)+relu, fc3(64->64)+relu, fc2(64->2)
__global__ __launch_bounds__(64) void head_kernel(
    const float* __restrict__ x7,
    const float* __restrict__ w1, const float* __restrict__ b1,
    const float* __restrict__ w3, const float* __restrict__ b3,
    const float* __restrict__ w2, const float* __restrict__ b2,
    float* __restrict__ out)
{
    const int b   = blockIdx.x;
    const int tid = threadIdx.x;
    __shared__ float xr[Cv * Hv];
    __shared__ float h1[64];
    __shared__ float h2s[64];

    const float* xrow = x7 + ((size_t)b * Tv + (Tv - 1)) * (Cv * Hv);
    if (tid < 48) ((float4*)xr)[tid] = ((const float4*)xrow)[tid];
    __syncthreads();

    float acc[4] = {0.f, 0.f, 0.f, 0.f};
    const float4* w4 = (const float4*)(w1 + tid * (Cv * Hv));
    const float4* x4 = (const float4*)xr;
    #pragma unroll
    for (int k = 0; k < 48; ++k) {
        float4 w = w4[k], xv = x4[k];
        acc[k & 3] += (w.x * xv.x + w.y * xv.y) + (w.z * xv.z + w.w * xv.w);
    }
    h1[tid] = fmaxf((acc[0] + acc[1]) + (acc[2] + acc[3]) + b1[tid], 0.0f);
    __syncthreads();

    float bcc[4] = {0.f, 0.f, 0.f, 0.f};
    const float4* w34 = (const float4*)(w3 + tid * 64);
    const float4* h14 = (const float4*)h1;
    #pragma unroll
    for (int k = 0; k < 16; ++k) {
        float4 w = w34[k], hv = h14[k];
        bcc[k & 3] += (w.x * hv.x + w.y * hv.y) + (w.z * hv.z + w.w * hv.w);
    }
    h2s[tid] = fmaxf((bcc[0] + bcc[1]) + (bcc[2] + bcc[3]) + b3[tid], 0.0f);
    __syncthreads();

    if (tid < 2) {
        float a2 = b2[tid];
        const float* w2r = w2 + tid * 64;
        #pragma unroll 4
        for (int k = 0; k < 64; ++k) a2 += w2r[k] * h2s[k];
        out[b * 2 + tid] = a2;
    }
}

extern "C" void kernel_launch(void* const* d_in, const int* in_sizes, int n_in,
                              void* d_out, int out_size, void* d_ws, size_t ws_size,
                              hipStream_t stream) {
    const float* x    = (const float*)d_in[0];
    const float* w_ih = (const float*)d_in[1];
    const float* w_hh = (const float*)d_in[2];
    const float* b_ih = (const float*)d_in[3];
    const float* b_hh = (const float*)d_in[4];
    const float* w1   = (const float*)d_in[5];
    const float* b1   = (const float*)d_in[6];
    const float* w3   = (const float*)d_in[7];
    const float* b3   = (const float*)d_in[8];
    const float* w2   = (const float*)d_in[9];
    const float* b2   = (const float*)d_in[10];

    float* out = (float*)d_out;
    float* x7  = out + (size_t)Bv * 2;   // tuple order: (out [B,2], x7 [B,T,192])

    // 384 groups: 64 batch-groups x 6 channels; 2 waves (128 thr) per group
    lstm_kernel<<<dim3((Bv / 16) * Cv), dim3(128), 0, stream>>>(x, w_ih, w_hh, b_ih, b_hh, x7);
    head_kernel<<<dim3(Bv), dim3(64), 0, stream>>>(x7, w1, b1, w3, b3, w2, b2, out);
}

// Round 10
// 393.206 us; speedup vs baseline: 1.2250x; 1.0055x over previous
//
#include <hip/hip_runtime.h>
#include <hip/hip_bf16.h>

// SeRNN forward: 6 channel-wise LSTMs (H=32) over T=256, B=1024, then MLP head.
// Outputs (concat): out [B,2] (2048 floats) then x7 [B,T,192].
//
// R2: VALU baseline 330. R4: trans merge 287. R5: pk_fma regressed. R7: fdot2
// 255 (f16-in/f32-acc proven safe). R8: 2-wave MFMA group 213 us — but the
// per-step __syncthreads forced a vmcnt(0) drain of the in-loop x7 store
// (~2000 cy/step, 3x the predicted chain).
// R9: ONE wave owns the whole 16-batch group (all 128 gate rows, 8 MFMA
//     tiles/step). No barrier at all: h LDS round-trip is same-wave
//     (lgkmcnt-ordered, lockstep => single buffer), x7 stores drain in the
//     background. Predicted chain ~650 cy/step -> ~75 us.

#define Bv 1024
#define Tv 256
#define Cv 6
#define Hv 32
#define Gv 128   // 4*H, PyTorch gate order i,f,g,o

#define L2E 1.442695041f   // log2(e)

typedef _Float16 f16x8 __attribute__((ext_vector_type(8)));
typedef float f32x4v __attribute__((ext_vector_type(4)));

__device__ __forceinline__ float fsig(float v) {
    return __builtin_amdgcn_rcpf(1.0f + __builtin_amdgcn_exp2f(v * -L2E));
}
__device__ __forceinline__ float ftanh2(float v) {  // tanh(x) = 2*sig(2x)-1
    float u = __builtin_amdgcn_rcpf(1.0f + __builtin_amdgcn_exp2f(v * (-2.0f * L2E)));
    return fmaf(u, 2.0f, -1.0f);
}

// One wave per (channel, 16-batch group). Lane: r16 = batch-in-group (B col /
// D col), grp = k-group & D row-group. 8 MFMA tiles cover gate rows 0..127.
__global__ __launch_bounds__(64) void lstm_kernel(
    const float* __restrict__ x,      // [B,T,C]
    const float* __restrict__ w_ih,   // [C,G]
    const float* __restrict__ w_hh,   // [C,G,H]
    const float* __restrict__ b_ih,   // [C,G]
    const float* __restrict__ b_hh,   // [C,G]
    float* __restrict__ x7)           // [B,T,C*H]
{
    // h state: [batch n][unit k] f16, row padded 32->40 (80 B) so the b128
    // reads land on the free 2-way bank alias. Single buffer (same-wave
    // lockstep: step-t read precedes step-t+1 write in program order).
    __shared__ _Float16 hlds[16][40];

    const int lane = threadIdx.x;     // 64 threads = 1 wave
    const int r16  = lane & 15;       // batch within group / D col
    const int grp  = lane >> 4;       // k-group / D row-group

    const int c  = blockIdx.x % Cv;               // channel
    const int nb = (blockIdx.x / Cv) * 16;        // batch base

    for (int i = lane; i < 16 * 40; i += 64) (&hlds[0][0])[i] = (_Float16)0.0f;

    // ---- A fragments: afrag[q][j] = W_hh[c][q*16 + r16][grp*8 + j] (f16) ----
    const float* whc = w_hh + (size_t)c * (Gv * Hv);
    f16x8 afrag[8];
    #pragma unroll
    for (int q = 0; q < 8; ++q) {
        const float* wr = whc + (q * 16 + r16) * Hv + grp * 8;
        float4 wa = *(const float4*)(wr);
        float4 wb = *(const float4*)(wr + 4);
        f16x8 a;
        a[0] = (_Float16)wa.x; a[1] = (_Float16)wa.y;
        a[2] = (_Float16)wa.z; a[3] = (_Float16)wa.w;
        a[4] = (_Float16)wb.x; a[5] = (_Float16)wb.y;
        a[6] = (_Float16)wb.z; a[7] = (_Float16)wb.w;
        afrag[q] = a;
    }
    // ---- bias + w_ih at D rows q*16 + grp*4 + r ----
    float4 bias4[8], wih4[8];
    #pragma unroll
    for (int q = 0; q < 8; ++q) {
        const int rb = q * 16 + grp * 4;
        float4 bi = *(const float4*)(b_ih + c * Gv + rb);
        float4 bh = *(const float4*)(b_hh + c * Gv + rb);
        bias4[q] = make_float4(bi.x + bh.x, bi.y + bh.y, bi.z + bh.z, bi.w + bh.w);
        wih4[q]  = *(const float4*)(w_ih + c * Gv + rb);
    }

    // cell state: unit u = q2*16 + grp*4 + r  ->  cst[q2*4+r], batch nb+r16
    float cst[8] = {0.f, 0.f, 0.f, 0.f, 0.f, 0.f, 0.f, 0.f};

    const float* xp = x + ((size_t)(nb + r16) * Tv) * Cv + c;
    float* op = x7 + ((size_t)(nb + r16) * Tv) * (Cv * Hv) + c * Hv + grp * 4;

    float xt = xp[0];
    for (int t = 0; t < Tv; ++t) {
        int tn = (t + 1 < Tv) ? (t + 1) : (Tv - 1);
        float xn = xp[tn * Cv];                    // prefetch next x_t

        // B fragment: h[k = grp*8 + j][n = r16] (same k-map as A -> correct)
        f16x8 bfrag = *(const f16x8*)(&hlds[r16][grp * 8]);

        f32x4v acc[8];
        #pragma unroll
        for (int q = 0; q < 8; ++q) {
            acc[q][0] = fmaf(xt, wih4[q].x, bias4[q].x);
            acc[q][1] = fmaf(xt, wih4[q].y, bias4[q].y);
            acc[q][2] = fmaf(xt, wih4[q].z, bias4[q].z);
            acc[q][3] = fmaf(xt, wih4[q].w, bias4[q].w);
            acc[q] = __builtin_amdgcn_mfma_f32_16x16x32_f16(afrag[q], bfrag, acc[q], 0, 0, 0);
        }

        // activations: unit u = q2*16 + grp*4 + r; i/f/g/o = tiles q2/q2+2/q2+4/q2+6
        float hv[8];
        #pragma unroll
        for (int q2 = 0; q2 < 2; ++q2) {
            #pragma unroll
            for (int r = 0; r < 4; ++r) {
                const int u = q2 * 4 + r;
                float i_s = fsig(acc[q2][r]);
                float f_s = fsig(acc[q2 + 2][r]);
                float g_t = ftanh2(acc[q2 + 4][r]);
                float o_s = fsig(acc[q2 + 6][r]);
                float cr  = fmaf(f_s, cst[u], i_s * g_t);
                cst[u] = cr;
                hv[u] = o_s * ftanh2(cr);
            }
        }

        // x7[b][t][c*32 + u]: units grp*4.. and 16+grp*4.. -> two dwordx4
        float* ot = op + (size_t)t * (Cv * Hv);
        *(float4*)(ot)      = make_float4(hv[0], hv[1], hv[2], hv[3]);
        *(float4*)(ot + 16) = make_float4(hv[4], hv[5], hv[6], hv[7]);

        // h -> f16 -> LDS for step t+1 (same wave; lgkmcnt ordering only)
        auto pk0 = __builtin_amdgcn_cvt_pkrtz(hv[0], hv[1]);
        auto pk1 = __builtin_amdgcn_cvt_pkrtz(hv[2], hv[3]);
        auto pk2 = __builtin_amdgcn_cvt_pkrtz(hv[4], hv[5]);
        auto pk3 = __builtin_amdgcn_cvt_pkrtz(hv[6], hv[7]);
        *(uint2*)(&hlds[r16][grp * 4]) =
            make_uint2(__builtin_bit_cast(unsigned int, pk0),
                       __builtin_bit_cast(unsigned int, pk1));
        *(uint2*)(&hlds[r16][16 + grp * 4]) =
            make_uint2(__builtin_bit_cast(unsigned int, pk2),
                       __builtin_bit_cast(unsigned int, pk3));

        xt = xn;
    }
}

// MLP head on x7[:, T-1, :]: fc1(192->64)+relu, fc3(64->64)+relu, fc2(64->2)
__global__ __launch_bounds__(64) void head_kernel(
    const float* __restrict__ x7,
    const float* __restrict__ w1, const float* __restrict__ b1,
    const float* __restrict__ w3, const float* __restrict__ b3,
    const float* __restrict__ w2, const float* __restrict__ b2,
    float* __restrict__ out)
{
    const int b   = blockIdx.x;
    const int tid = threadIdx.x;
    __shared__ float xr[Cv * Hv];
    __shared__ float h1[64];
    __shared__ float h2s[64];

    const float* xrow = x7 + ((size_t)b * Tv + (Tv - 1)) * (Cv * Hv);
    if (tid < 48) ((float4*)xr)[tid] = ((const float4*)xrow)[tid];
    __syncthreads();

    float acc[4] = {0.f, 0.f, 0.f, 0.f};
    const float4* w4 = (const float4*)(w1 + tid * (Cv * Hv));
    const float4* x4 = (const float4*)xr;
    #pragma unroll
    for (int k = 0; k < 48; ++k) {
        float4 w = w4[k], xv = x4[k];
        acc[k & 3] += (w.x * xv.x + w.y * xv.y) + (w.z * xv.z + w.w * xv.w);
    }
    h1[tid] = fmaxf((acc[0] + acc[1]) + (acc[2] + acc[3]) + b1[tid], 0.0f);
    __syncthreads();

    float bcc[4] = {0.f, 0.f, 0.f, 0.f};
    const float4* w34 = (const float4*)(w3 + tid * 64);
    const float4* h14 = (const float4*)h1;
    #pragma unroll
    for (int k = 0; k < 16; ++k) {
        float4 w = w34[k], hv = h14[k];
        bcc[k & 3] += (w.x * hv.x + w.y * hv.y) + (w.z * hv.z + w.w * hv.w);
    }
    h2s[tid] = fmaxf((bcc[0] + bcc[1]) + (bcc[2] + bcc[3]) + b3[tid], 0.0f);
    __syncthreads();

    if (tid < 2) {
        float a2 = b2[tid];
        const float* w2r = w2 + tid * 64;
        #pragma unroll 4
        for (int k = 0; k < 64; ++k) a2 += w2r[k] * h2s[k];
        out[b * 2 + tid] = a2;
    }
}

extern "C" void kernel_launch(void* const* d_in, const int* in_sizes, int n_in,
                              void* d_out, int out_size, void* d_ws, size_t ws_size,
                              hipStream_t stream) {
    const float* x    = (const float*)d_in[0];
    const float* w_ih = (const float*)d_in[1];
    const float* w_hh = (const float*)d_in[2];
    const float* b_ih = (const float*)d_in[3];
    const float* b_hh = (const float*)d_in[4];
    const float* w1   = (const float*)d_in[5];
    const float* b1   = (const float*)d_in[6];
    const float* w3   = (const float*)d_in[7];
    const float* b3   = (const float*)d_in[8];
    const float* w2   = (const float*)d_in[9];
    const float* b2   = (const float*)d_in[10];

    float* out = (float*)d_out;
    float* x7  = out + (size_t)Bv * 2;   // tuple order: (out [B,2], x7 [B,T,192])

    // 384 single-wave groups: 64 batch-groups x 6 channels
    lstm_kernel<<<dim3((Bv / 16) * Cv), dim3(64), 0, stream>>>(x, w_ih, w_hh, b_ih, b_hh, x7);
    head_kernel<<<dim3(Bv), dim3(64), 0, stream>>>(x7, w1, b1, w3, b3, w2, b2, out);
}